// Round 5
// baseline (23711.917 us; speedup 1.0000x reference)
//
#include <hip/hip_runtime.h>
#include <cmath>

// ---------------------------------------------------------------------------
// MaSST: memory-augmented GRU scan. T=128, B=32, F=500, H=512, M=64, HEAD=64.
// Round-4 (PASSED, 14.4ms) + round-5 changes:
//  - LDS-stage read-only weights ONCE pre-loop (w_hh slice / aux slices /
//    hfc_w1+w2) -> immune to the per-barrier L2 invalidation (FETCH driver).
//  - distributed barrier arrival: 32 padded counters + parallel polling
//    (was: 256 far-atomics on ONE line per barrier).
// Coherence semantics identical to round 4 (per-WG threadfence release/acquire).
// ---------------------------------------------------------------------------

#define NWG 256
#define NEGV -9999999.0f

constexpr size_t OXP   = 0;                         // xp [4096,512]
constexpr size_t OGIXM = OXP   + 4096ull*512;       // xp@w_ih[:512]+b_ih [4096,1536]
constexpr size_t OPI   = OGIXM + 4096ull*1536;      // xp@w_ih[512:]      [4096,1536]
constexpr size_t OGIXA = OPI   + 4096ull*1536;      // xp@aux_wih[:512]+aux_bih [4096,390]
constexpr size_t OIHID = OGIXA + 4096ull*390;       // relu(xp@ifc_w1+b1) [4096,32]
constexpr size_t OIMLPX= OIHID + 4096ull*32;        // sigmoid(ihid@ifc_w2+b2) [4096,64]
constexpr size_t OHT   = OIMLPX+ 4096ull*64;        // h transposed [512][32]
constexpr size_t OAUXT = OHT   + 512ull*32;         // aux transposed [130][32]
constexpr size_t ORH   = OAUXT + 130ull*32;         // read_head [32][130]
constexpr size_t OG1   = ORH   + 130ull*32;         // h@Whh1+b_hh [32][1536]
constexpr size_t OG2   = OG1   + 32ull*1536;        // h@Whh2      [32][1536]
constexpr size_t OHG2  = OG2   + 32ull*1536;        // cache: hmem_slot@Whh2 [32][64][1536]
constexpr size_t OIC   = OHG2  + 32ull*64*1536;     // i mlp cache [32][64][64]
constexpr size_t OHC   = OIC   + 32ull*64*64;       // h mlp cache [32][64][64]
constexpr size_t OILU  = OHC   + 32ull*64*64;       // [32][64]
constexpr size_t OHLU  = OILU  + 2048;
constexpr size_t OISL  = OHLU  + 2048;              // int: slot -> time (or -1)
constexpr size_t OHID  = OISL  + 2048;              // hidden dbuf [2][32][32]
constexpr size_t OPEND = OHID  + 2048;              // int pend [32][8]
constexpr size_t OBARS = OPEND + 256;               // int bars[32*16] (64B-spaced)
constexpr size_t OYS   = OBARS + 512;               // ys [4096,512]
constexpr size_t OTOT  = OYS   + 4096ull*512;

__device__ float g_mem[OTOT];

__device__ __forceinline__ float sigm(float x){ return 1.0f/(1.0f+expf(-x)); }

// ---------------------------------------------------------------------------
__global__ void k_init() {
  size_t i = (size_t)blockIdx.x*blockDim.x + threadIdx.x;
  size_t st = (size_t)gridDim.x*blockDim.x;
  for (size_t k=i; k<32ull*64*1536; k+=st) g_mem[OHG2+k]=0.f;
  for (size_t k=i; k<32ull*64*64; k+=st){ g_mem[OIC+k]=0.5f; g_mem[OHC+k]=0.5f; } // MLP(0)=sigmoid(0)=0.5
  for (size_t k=i; k<2048; k+=st){ g_mem[OILU+k]=NEGV; g_mem[OHLU+k]=NEGV; ((int*)(g_mem+OISL))[k]=-1; }
  for (size_t k=i; k<512ull*32; k+=st) g_mem[OHT+k]=0.f;
  for (size_t k=i; k<130ull*32; k+=st) g_mem[OAUXT+k]=0.f;
  for (size_t k=i; k<768; k+=st) ((int*)(g_mem+OPEND))[k]=0;   // pend(256)+bars(512)
}

// ---------------------------------------------------------------------------
// Generic fp32 tiled GEMM: C[M=4096, N] = act(A[4096,K] @ B[K,N] + bias)
// act: 0 none, 1 relu, 2 sigmoid.
__global__ __launch_bounds__(256) void k_gemm(
    const float* __restrict__ A, int lda,
    const float* __restrict__ B, int ldb,
    const float* __restrict__ bias,
    float* __restrict__ C, int ldc,
    int N, int K, int act)
{
  __shared__ float As[16][64];
  __shared__ float Bs[16][68];
  const int tid = threadIdx.x;
  const int row0 = blockIdx.x*64;
  const int col0 = blockIdx.y*64;
  const int tm = tid>>4, tn = tid&15;
  const int am = tid>>2, akq = tid&3;
  const int bk = tid>>4, bnq = tid&15;
  float acc[4][4] = {};
  for (int k0=0; k0<K; k0+=16) {
    {
      int ak = k0 + akq*4;
      const float* Ap = A + (size_t)(row0+am)*lda + ak;
      float4 av;
      if (ak+3 < K) av = *(const float4*)Ap;
      else {
        av.x=(ak+0<K)?Ap[0]:0.f; av.y=(ak+1<K)?Ap[1]:0.f;
        av.z=(ak+2<K)?Ap[2]:0.f; av.w=(ak+3<K)?Ap[3]:0.f;
      }
      As[akq*4+0][am]=av.x; As[akq*4+1][am]=av.y; As[akq*4+2][am]=av.z; As[akq*4+3][am]=av.w;
    }
    {
      int kk = k0 + bk;
      int cb = col0 + bnq*4;
      float4 bv = {0.f,0.f,0.f,0.f};
      if (kk < K) {
        const float* Bp = B + (size_t)kk*ldb + cb;
        if (cb+3 < N && ((((size_t)kk*ldb + (size_t)cb)&3)==0)) bv = *(const float4*)Bp;
        else {
          bv.x=(cb+0<N)?Bp[0]:0.f; bv.y=(cb+1<N)?Bp[1]:0.f;
          bv.z=(cb+2<N)?Bp[2]:0.f; bv.w=(cb+3<N)?Bp[3]:0.f;
        }
      }
      Bs[bk][bnq*4+0]=bv.x; Bs[bk][bnq*4+1]=bv.y; Bs[bk][bnq*4+2]=bv.z; Bs[bk][bnq*4+3]=bv.w;
    }
    __syncthreads();
    #pragma unroll
    for (int k=0;k<16;++k) {
      float a0=As[k][tm*4+0], a1=As[k][tm*4+1], a2=As[k][tm*4+2], a3=As[k][tm*4+3];
      float b0=Bs[k][tn*4+0], b1=Bs[k][tn*4+1], b2=Bs[k][tn*4+2], b3=Bs[k][tn*4+3];
      acc[0][0]=fmaf(a0,b0,acc[0][0]); acc[0][1]=fmaf(a0,b1,acc[0][1]);
      acc[0][2]=fmaf(a0,b2,acc[0][2]); acc[0][3]=fmaf(a0,b3,acc[0][3]);
      acc[1][0]=fmaf(a1,b0,acc[1][0]); acc[1][1]=fmaf(a1,b1,acc[1][1]);
      acc[1][2]=fmaf(a1,b2,acc[1][2]); acc[1][3]=fmaf(a1,b3,acc[1][3]);
      acc[2][0]=fmaf(a2,b0,acc[2][0]); acc[2][1]=fmaf(a2,b1,acc[2][1]);
      acc[2][2]=fmaf(a2,b2,acc[2][2]); acc[2][3]=fmaf(a2,b3,acc[2][3]);
      acc[3][0]=fmaf(a3,b0,acc[3][0]); acc[3][1]=fmaf(a3,b1,acc[3][1]);
      acc[3][2]=fmaf(a3,b2,acc[3][2]); acc[3][3]=fmaf(a3,b3,acc[3][3]);
    }
    __syncthreads();
  }
  for (int i=0;i<4;++i)
    for (int j2=0;j2<4;++j2) {
      int r = row0+tm*4+i, c = col0+tn*4+j2;
      if (c<N) {
        float v = acc[i][j2] + (bias? bias[c]:0.f);
        if (act==1) v = fmaxf(v,0.f);
        else if (act==2) v = 1.f/(1.f+expf(-v));
        C[(size_t)r*ldc + c] = v;
      }
    }
}

// ---------------------------------------------------------------------------
// Global barrier, round-4 fence semantics, distributed arrival:
// WG w adds (after release threadfence) to bars[(w>>3)*16]; threads 0..31
// poll one counter each (RELAXED - no cache maintenance per poll); one
// acquire threadfence after all counters reach target.
__device__ __forceinline__ void gbar(int n, int wg, int& alive, int* s_bail) {
  __syncthreads();
  int* bars = (int*)(g_mem+OBARS);
  if (alive) {
    if (threadIdx.x==0) { __threadfence(); atomicAdd(&bars[(wg>>3)*16], 1); }
    if (threadIdx.x<32) {
      const int target = n*8;
      int guard = 0;
      while (__hip_atomic_load(&bars[threadIdx.x*16], __ATOMIC_RELAXED, __HIP_MEMORY_SCOPE_AGENT) < target) {
        __builtin_amdgcn_s_sleep(2);
        if (++guard > (1<<20)) { *s_bail = 1; break; }   // bail instead of hanging
      }
    }
  }
  __syncthreads();
  if (*s_bail) alive = 0;
  else if (threadIdx.x==0 && alive) __threadfence();   // acquire: one inv
  __syncthreads();
}

// ---------------------------------------------------------------------------
__global__ __launch_bounds__(256,1) void k_scan(
    const float* __restrict__ w_hh, const float* __restrict__ b_hh,
    const float* __restrict__ aux_wih, const float* __restrict__ aux_whh,
    const float* __restrict__ aux_bhh,
    const float* __restrict__ hfc_w1, const float* __restrict__ hfc_b1,
    const float* __restrict__ hfc_w2, const float* __restrict__ hfc_b2,
    const float* __restrict__ gum_i, const float* __restrict__ gum_h,
    const int* __restrict__ length)
{
  const int wg  = blockIdx.x;
  const int tid = threadIdx.x;
  float* const mem = g_mem;
  int*  const islot = (int*)(mem+OISL);
  int*  const pend  = (int*)(mem+OPEND);

  extern __shared__ __align__(16) float s_blob[];   // 32768 floats (128 KB)
  __shared__ float s_red[2][4][64];
  __shared__ float s_sp[5][4][2][32];
  __shared__ float s_ph[32][9];
  __shared__ float s_rhs[132];
  __shared__ float s_sv[128];
  __shared__ int   s_si[128];
  __shared__ int   s_sel[4];
  __shared__ int   s_pd[8];
  __shared__ int   s_bail;

  if (tid==0) s_bail = 0;

  // ===== one-time LDS staging of read-only weights (fence-immune) ==========
  if (wg < 192) {
    const int cg = wg>>2;
    const int isG2c = (cg>=24);
    const int rowb  = isG2c? 512 : 0;
    const int colb  = cg*64 - (isG2c? 1536 : 0);
    for (int i4 = tid; i4 < 8192; i4 += 256) {            // 512k x 64col floats
      const int k = i4>>4, c4 = i4&15;
      const float4 v = *(const float4*)&w_hh[(size_t)(rowb+k)*1536 + colb + c4*4];
      *(float4*)&s_blob[k*64 + c4*4] = v;
    }
  } else if (wg < 224) {
    const int a = wg-192;
    const int c0 = (a*130)>>5, c1 = ((a+1)*130)>>5;
    const int nc = c1-c0;
    const int w3 = nc*3;
    float* s_aw  = s_blob;            // [512][16]: h-part cols (rcl*3+gate)
    float* s_aw2 = s_blob + 8192;     // [130][16]: aux-part cols
    for (int i = tid; i < 512*w3; i += 256) {
      const int k = i/w3, r = i - k*w3;
      const int rcl = r/3, gate = r - rcl*3;              // gate in {0,1,2}
      const int gc = (gate==2? 260 : gate*130) + (c0+rcl);
      s_aw[k*16 + r] = aux_wih[(size_t)(512+k)*390 + gc];
    }
    for (int i = tid; i < 130*w3; i += 256) {
      const int k = i/w3, r = i - k*w3;
      const int rcl = r/3, q = r - rcl*3;                 // q in {0,1,2}
      const int gate = (q==2)? 3 : q;                     // maps to {0,1,3}
      const int gc = (gate==3? 260 : gate*130) + (c0+rcl);
      s_aw2[k*16 + r] = aux_whh[(size_t)k*390 + gc];
    }
  } else {
    float* s_w1 = s_blob;             // hfc_w1 [512][32]
    float* s_w2 = s_blob + 16384;     // hfc_w2 [32][64]
    for (int i4 = tid; i4 < 4096; i4 += 256) ((float4*)s_w1)[i4] = ((const float4*)hfc_w1)[i4];
    for (int i4 = tid; i4 < 512;  i4 += 256) ((float4*)s_w2)[i4] = ((const float4*)hfc_w2)[i4];
  }
  __syncthreads();

  int alive = 1;

  #pragma unroll 1
  for (int t=0; t<128; ++t) {
    // ================= H-phase: everything depending only on carry h/aux ====
    if (wg < 192) {
      // G1 = h@Whh1 + b_hh ; G2 = h@Whh2.  3072 virtual cols over 48 groups.
      const int cg = wg>>2, bg = wg&3;
      const int wave = tid>>6, lane = tid&63;
      const int vcol = cg*64 + lane;
      const int isG2 = vcol>=1536;
      const int col  = isG2? vcol-1536 : vcol;
      const int bh = wave>>1, kh = wave&1;
      const int b0 = bg*8 + bh*4;
      const float* hTp = mem+OHT;
      float a0=0.f,a1=0.f,a2=0.f,a3=0.f;
      const int kbeg = kh*256;
      #pragma unroll 8
      for (int k=kbeg; k<kbeg+256; ++k) {
        const float w = s_blob[k*64 + lane];               // LDS (was w_hh)
        const float4 hv = *(const float4*)(hTp + (k<<5) + b0);
        a0 = fmaf(w,hv.x,a0); a1 = fmaf(w,hv.y,a1);
        a2 = fmaf(w,hv.z,a2); a3 = fmaf(w,hv.w,a3);
      }
      if (kh) { s_red[bh][0][lane]=a0; s_red[bh][1][lane]=a1; s_red[bh][2][lane]=a2; s_red[bh][3][lane]=a3; }
      __syncthreads();
      if (!kh) {
        a0+=s_red[bh][0][lane]; a1+=s_red[bh][1][lane]; a2+=s_red[bh][2][lane]; a3+=s_red[bh][3][lane];
        const float bias = isG2 ? 0.f : b_hh[vcol];
        float* Gp = mem + (isG2? OG2 : OG1);
        Gp[(size_t)(b0+0)*1536+col]=a0+bias;
        Gp[(size_t)(b0+1)*1536+col]=a1+bias;
        Gp[(size_t)(b0+2)*1536+col]=a2+bias;
        Gp[(size_t)(b0+3)*1536+col]=a3+bias;
      }
    } else if (wg < 224) {
      // aux GRU read_head. rh-cols [c0,c1) for this WG.
      const int a = wg-192;
      const int c0 = (a*130)>>5, c1 = ((a+1)*130)>>5;
      const int nc = c1-c0;
      const int nt = nc*256;
      const float* hTp = mem+OHT;
      const float* axp = mem+OAUXT;
      const float* s_aw  = s_blob;
      const float* s_aw2 = s_blob + 8192;
      for (int task=tid; task<nt; task+=256) {
        const int b=task&31, kh=(task>>5)&1, gate=(task>>6)&3, rcl=task>>8;
        float acc=0.f;
        if (gate != 3) {                       // h-part dot (r,z merged; n separate)
          const int kb = kh*256;
          #pragma unroll 8
          for (int k=kb;k<kb+256;++k) acc = fmaf(hTp[(k<<5)+b], s_aw[k*16 + rcl*3+gate], acc);
        }
        if (gate != 2) {                       // aux-part dot
          const int q = (gate==3)? 2 : gate;
          const int kb = kh*65;
          for (int k=kb;k<kb+65;++k) acc = fmaf(axp[(k<<5)+b], s_aw2[k*16 + rcl*3+q], acc);
        }
        s_sp[rcl][gate][kh][b] = acc;
      }
      __syncthreads();
      for (int task=tid; task<nc*32; task+=256) {
        const int b=task&31, rcl=task>>5;
        const int c=c0+rcl;
        const size_t base=((size_t)t*32+b)*390;
        const float r = sigm(mem[OGIXA+base+c]     + aux_bhh[c]     + s_sp[rcl][0][0][b]+s_sp[rcl][0][1][b]);
        const float z = sigm(mem[OGIXA+base+130+c] + aux_bhh[130+c] + s_sp[rcl][1][0][b]+s_sp[rcl][1][1][b]);
        const float gin = mem[OGIXA+base+260+c] + s_sp[rcl][2][0][b]+s_sp[rcl][2][1][b];
        const float ghn = aux_bhh[260+c]        + s_sp[rcl][3][0][b]+s_sp[rcl][3][1][b];
        const float n = tanhf(gin + r*ghn);
        mem[ORH + (size_t)b*130 + c] = (1.f-z)*n + z*axp[(c<<5)+b];
      }
    } else {
      // mlph WG: deferred cache updates from step t-1, then hidden = relu(h@hfc_w1)
      const int b = wg-224;
      const float* s_w1 = s_blob;
      const float* s_w2 = s_blob + 16384;
      if (tid<8) s_pd[tid] = pend[b*8+tid];
      __syncthreads();
      if (s_pd[0]) {
        const int tp=s_pd[1], isel=s_pd[2], hsel=s_pd[3], wsi=s_pd[4], wsh=s_pd[5];
        if (tid<64) {
          mem[OIC + ((size_t)b*64+wsi)*64 + tid] = mem[OIMLPX + ((size_t)tp*32+b)*64 + tid];
        } else if (tid<128) {
          const int j2=tid-64;
          float s = hfc_b2[j2];
          const float* hid = mem + OHID + (size_t)(tp&1)*1024 + b*32;
          #pragma unroll 8
          for (int q=0;q<32;++q) s = fmaf(hid[q], s_w2[q*64+j2], s);
          mem[OHC + ((size_t)b*64+wsh)*64 + j2] = sigm(s);
        } else if (tid<192) {
          const int m=tid-128;
          const float v = mem[OILU + b*64 + m];
          mem[OILU + b*64 + m] = (m==isel)? 0.f : (v-1.f);
        } else {
          const int m=tid-192;
          const float v = mem[OHLU + b*64 + m];
          mem[OHLU + b*64 + m] = (m==hsel)? 0.f : (v-1.f);
        }
        if (tid==0) islot[b*64+wsi] = tp;
      }
      __syncthreads();
      { // hidden_new
        const int j = tid&31, kq = tid>>5;
        const float* hTp = mem+OHT;
        float acc=0.f;
        const int kb = kq*64;
        #pragma unroll 4
        for (int k=kb;k<kb+64;++k) acc = fmaf(hTp[(k<<5)+b], s_w1[k*32+j], acc);
        s_ph[j][kq]=acc;
      }
      __syncthreads();
      if (tid<32) {
        float s = hfc_b1[tid];
        #pragma unroll
        for (int q=0;q<8;++q) s += s_ph[tid][q];
        mem[OHID + (size_t)(t&1)*1024 + b*32 + tid] = fmaxf(s,0.f);
      }
    }
    gbar(2*t+1, wg, alive, &s_bail);

    // ================= S-phase: scores, argmax, gather, gate combine ========
    {
      const int b = wg>>3, j = wg&7;
      if (tid<130) s_rhs[tid] = mem[ORH + (size_t)b*130 + tid];
      __syncthreads();
      if (tid<128) {
        const int head=tid>>6, m=tid&63;
        const float* cache = mem + (head? OHC:OIC) + ((size_t)b*64+m)*64;
        const float* rh = s_rhs + head*65;
        float acc=0.f;
        #pragma unroll 16
        for (int k=0;k<64;++k) acc = fmaf(rh[k], cache[k], acc);
        const float lu = mem[(head? OHLU:OILU) + b*64 + m];
        acc += rh[64]*sigm(lu);
        acc += (head? gum_h:gum_i)[((size_t)t*32+b)*64+m];
        s_sv[tid]=acc; s_si[tid]=m;
      }
      __syncthreads();
      for (int off=32; off>0; off>>=1) {
        if (tid<128 && (tid&63)<off) {
          const float v2=s_sv[tid+off]; const int i2=s_si[tid+off];
          if (v2>s_sv[tid] || (v2==s_sv[tid] && i2<s_si[tid])) { s_sv[tid]=v2; s_si[tid]=i2; }
        }
        __syncthreads();
      }
      if (tid==0) { s_sel[0]=s_si[0]; s_sel[1]=s_si[64]; s_sel[2]=islot[b*64+s_si[0]]; }
      __syncthreads();
      const int isel=s_sel[0], hsel=s_sel[1], tsel=s_sel[2];
      const int wsi = (t<64)? t : isel;
      const int wsh = (t<64)? t : hsel;
      const int len = length[b];
      if (tid<64) {
        const int g = j*64 + tid;
        const size_t base=((size_t)t*32+b)*1536;
        float wi0=mem[OGIXM+base+g], wi1=mem[OGIXM+base+512+g], wi2=mem[OGIXM+base+1024+g];
        if (tsel>=0) {
          const size_t pb=((size_t)tsel*32+b)*1536;
          wi0+=mem[OPI+pb+g]; wi1+=mem[OPI+pb+512+g]; wi2+=mem[OPI+pb+1024+g];
        }
        const size_t hb=((size_t)b*64+hsel)*1536;
        const size_t g1b=(size_t)b*1536;
        const float wh0=mem[OG1+g1b+g]      + mem[OHG2+hb+g];
        const float wh1=mem[OG1+g1b+512+g]  + mem[OHG2+hb+512+g];
        const float wh2=mem[OG1+g1b+1024+g] + mem[OHG2+hb+1024+g];
        const float r=sigm(wi0+wh0), z=sigm(wi1+wh1);
        const float n=tanhf(wi2 + r*wh2);
        const float hold=mem[OHT + (g<<5) + b];
        const float h1=(1.f-z)*n + z*hold;
        const float hn = (t<len)? h1 : hold;
        mem[OHT + (g<<5) + b] = hn;
        mem[OYS + ((size_t)t*32+b)*512 + g] = hn;
        // hmem slot write: cache h@Whh2 of carry-in h at wsh (read of hsel above
        // and this write touch the same col-slice only within THIS WG).
        const size_t wb=((size_t)b*64+wsh)*1536;
        mem[OHG2+wb+g]      = mem[OG2+g1b+g];
        mem[OHG2+wb+512+g]  = mem[OG2+g1b+512+g];
        mem[OHG2+wb+1024+g] = mem[OG2+g1b+1024+g];
      } else if (j==1 && tid>=64 && tid<194) {
        const int c=tid-64;
        if (t<len) mem[OAUXT + (c<<5) + b] = s_rhs[c];
      } else if (j==0 && tid==200) {
        pend[b*8+0]=1; pend[b*8+1]=t; pend[b*8+2]=isel; pend[b*8+3]=hsel;
        pend[b*8+4]=wsi; pend[b*8+5]=wsh;
      }
    }
    gbar(2*t+2, wg, alive, &s_bail);
  }
}

// ---------------------------------------------------------------------------
extern "C" void kernel_launch(void* const* d_in, const int* in_sizes, int n_in,
                              void* d_out, int out_size, void* d_ws, size_t ws_size,
                              hipStream_t stream)
{
  (void)in_sizes; (void)n_in; (void)out_size; (void)d_ws; (void)ws_size;
  const float* x      = (const float*)d_in[0];
  const int*   length = (const int*)  d_in[1];
  const float* fc1_w  = (const float*)d_in[2];
  const float* fc1_b  = (const float*)d_in[3];
  const float* w_ih   = (const float*)d_in[4];
  const float* w_hh   = (const float*)d_in[5];
  const float* b_ih   = (const float*)d_in[6];
  const float* b_hh   = (const float*)d_in[7];
  const float* aux_wih= (const float*)d_in[8];
  const float* aux_whh= (const float*)d_in[9];
  const float* aux_bih= (const float*)d_in[10];
  const float* aux_bhh= (const float*)d_in[11];
  const float* ifc_w1 = (const float*)d_in[12];
  const float* ifc_b1 = (const float*)d_in[13];
  const float* ifc_w2 = (const float*)d_in[14];
  const float* ifc_b2 = (const float*)d_in[15];
  const float* hfc_w1 = (const float*)d_in[16];
  const float* hfc_b1 = (const float*)d_in[17];
  const float* hfc_w2 = (const float*)d_in[18];
  const float* hfc_b2 = (const float*)d_in[19];
  const float* fc_w   = (const float*)d_in[20];
  const float* fc_b   = (const float*)d_in[21];
  const float* gum_i  = (const float*)d_in[22];
  const float* gum_h  = (const float*)d_in[23];
  float* out = (float*)d_out;

  float* gm = nullptr;
  hipGetSymbolAddress((void**)&gm, HIP_SYMBOL(g_mem));

  static bool attr_done = false;
  if (!attr_done) {
    hipFuncSetAttribute((const void*)k_scan,
                        hipFuncAttributeMaxDynamicSharedMemorySize, 131072);
    attr_done = true;
  }

  k_init<<<2048,256,0,stream>>>();
  // xp = x @ fc1_w + fc1_b
  k_gemm<<<dim3(64,8),256,0,stream>>>(x,500, fc1_w,512, fc1_b, gm+OXP,512, 512,500, 0);
  // gix_main = xp @ w_ih[:512] + b_ih
  k_gemm<<<dim3(64,24),256,0,stream>>>(gm+OXP,512, w_ih,1536, b_ih, gm+OGIXM,1536, 1536,512, 0);
  // P_i = xp @ w_ih[512:]
  k_gemm<<<dim3(64,24),256,0,stream>>>(gm+OXP,512, w_ih+(size_t)512*1536,1536, nullptr, gm+OPI,1536, 1536,512, 0);
  // gix_aux = xp @ aux_wih[:512] + aux_bih
  k_gemm<<<dim3(64,7),256,0,stream>>>(gm+OXP,512, aux_wih,390, aux_bih, gm+OGIXA,390, 390,512, 0);
  // ihid = relu(xp @ ifc_w1 + ifc_b1)
  k_gemm<<<dim3(64,1),256,0,stream>>>(gm+OXP,512, ifc_w1,32, ifc_b1, gm+OIHID,32, 32,512, 1);
  // imlp_x = sigmoid(ihid @ ifc_w2 + ifc_b2)
  k_gemm<<<dim3(64,1),256,0,stream>>>(gm+OIHID,32, ifc_w2,64, ifc_b2, gm+OIMLPX,64, 64,32, 2);
  // sequential scan (persistent kernel, 2 global barriers per step)
  k_scan<<<NWG,256,131072,stream>>>(w_hh,b_hh,aux_wih,aux_whh,aux_bhh,
                                    hfc_w1,hfc_b1,hfc_w2,hfc_b2,gum_i,gum_h,length);
  // out = ys @ fc_w + fc_b
  k_gemm<<<dim3(64,1),256,0,stream>>>(gm+OYS,512, fc_w,48, fc_b, out,48, 48,512, 0);
}

// Round 6
// 6221.371 us; speedup vs baseline: 3.8114x; 3.8114x over previous
//
#include <hip/hip_runtime.h>
#include <cmath>

// ---------------------------------------------------------------------------
// MaSST: memory-augmented GRU scan. T=128, B=32, F=500, H=512, M=64, HEAD=64.
// Round-6 "zero-fence" design:
//  - NO threadfences anywhere (round-5 counters: fences, not HBM, dominate).
//  - cross-WG mutable data: sc0sc1 (SYSTEM relaxed atomic) on BOTH sides,
//    lane-coalesced; LDS staging for bulk reads (h, aux carries).
//  - read-only weights/precomputed: normal cached loads (L2 stays warm —
//    nothing ever invalidates it).
//  - score caches/lu/islot live persistently in per-batch WG LDS: scores,
//    argmax, gather, gate-combine all inside ONE WG per batch (sel local).
//  - barrier: vmcnt(0) + atomicAdd + relaxed poll on 32 padded counters.
// ---------------------------------------------------------------------------

#define NWG 256
#define NEGV -9999999.0f

constexpr size_t OXP   = 0;                         // xp [4096,512]
constexpr size_t OGIXM = OXP   + 4096ull*512;       // xp@w_ih[:512]+b_ih [4096,1536]
constexpr size_t OPI   = OGIXM + 4096ull*1536;      // xp@w_ih[512:]      [4096,1536]
constexpr size_t OGIXA = OPI   + 4096ull*1536;      // xp@aux_wih[:512]+aux_bih [4096,390]
constexpr size_t OIHID = OGIXA + 4096ull*390;       // relu(xp@ifc_w1+b1) [4096,32]
constexpr size_t OIMLPX= OIHID + 4096ull*32;        // sigmoid(ihid@ifc_w2+b2) [4096,64]
constexpr size_t OHTS  = OIMLPX+ 4096ull*64;        // h dbuf [2][32][512] batch-major
constexpr size_t OAX   = OHTS  + 2ull*32*512;       // aux dbuf [2][32][132]
constexpr size_t ORH   = OAX   + 2ull*32*132;       // read_head [132][32] c-major
constexpr size_t OG1   = ORH   + 132ull*32;         // h@Whh1+b_hh [32][1536]
constexpr size_t OG2   = OG1   + 32ull*1536;        // h@Whh2      [32][1536]
constexpr size_t OHG2  = OG2   + 32ull*1536;        // hmem_slot@Whh2 [32][64][1536] (batch-WG private)
constexpr size_t OBARS = OHG2  + 32ull*64*1536;     // 512 ints (32 ctr x 16 pad)
constexpr size_t OYS   = OBARS + 512;               // ys [4096,512]
constexpr size_t OTOT  = OYS   + 4096ull*512;

__device__ float g_mem[OTOT];

__device__ __forceinline__ float sigm(float x){ return 1.0f/(1.0f+expf(-x)); }

// system-scope relaxed (sc0 sc1): bypass L1/L2, coherent at MALL, no fences
__device__ __forceinline__ float ldc1(const float* p){
  return __hip_atomic_load(p, __ATOMIC_RELAXED, __HIP_MEMORY_SCOPE_SYSTEM);
}
__device__ __forceinline__ void stc1(float* p, float v){
  __hip_atomic_store(p, v, __ATOMIC_RELAXED, __HIP_MEMORY_SCOPE_SYSTEM);
}

// ---------------------------------------------------------------------------
__global__ void k_init() {
  size_t i = (size_t)blockIdx.x*blockDim.x + threadIdx.x;
  size_t st = (size_t)gridDim.x*blockDim.x;
  for (size_t k=i; k<32ull*64*1536; k+=st) g_mem[OHG2+k]=0.f;
  for (size_t k=i; k<32ull*512; k+=st) g_mem[OHTS+k]=0.f;     // h dbuf slot 0
  for (size_t k=i; k<32ull*132; k+=st) g_mem[OAX+k]=0.f;      // aux dbuf slot 0
  for (size_t k=i; k<512; k+=st) ((int*)(g_mem+OBARS))[k]=0;
}

// ---------------------------------------------------------------------------
// Generic fp32 tiled GEMM: C[M=4096, N] = act(A[4096,K] @ B[K,N] + bias)
__global__ __launch_bounds__(256) void k_gemm(
    const float* __restrict__ A, int lda,
    const float* __restrict__ B, int ldb,
    const float* __restrict__ bias,
    float* __restrict__ C, int ldc,
    int N, int K, int act)
{
  __shared__ float As[16][64];
  __shared__ float Bs[16][68];
  const int tid = threadIdx.x;
  const int row0 = blockIdx.x*64;
  const int col0 = blockIdx.y*64;
  const int tm = tid>>4, tn = tid&15;
  const int am = tid>>2, akq = tid&3;
  const int bk = tid>>4, bnq = tid&15;
  float acc[4][4] = {};
  for (int k0=0; k0<K; k0+=16) {
    {
      int ak = k0 + akq*4;
      const float* Ap = A + (size_t)(row0+am)*lda + ak;
      float4 av;
      if (ak+3 < K) av = *(const float4*)Ap;
      else {
        av.x=(ak+0<K)?Ap[0]:0.f; av.y=(ak+1<K)?Ap[1]:0.f;
        av.z=(ak+2<K)?Ap[2]:0.f; av.w=(ak+3<K)?Ap[3]:0.f;
      }
      As[akq*4+0][am]=av.x; As[akq*4+1][am]=av.y; As[akq*4+2][am]=av.z; As[akq*4+3][am]=av.w;
    }
    {
      int kk = k0 + bk;
      int cb = col0 + bnq*4;
      float4 bv = {0.f,0.f,0.f,0.f};
      if (kk < K) {
        const float* Bp = B + (size_t)kk*ldb + cb;
        if (cb+3 < N && ((((size_t)kk*ldb + (size_t)cb)&3)==0)) bv = *(const float4*)Bp;
        else {
          bv.x=(cb+0<N)?Bp[0]:0.f; bv.y=(cb+1<N)?Bp[1]:0.f;
          bv.z=(cb+2<N)?Bp[2]:0.f; bv.w=(cb+3<N)?Bp[3]:0.f;
        }
      }
      Bs[bk][bnq*4+0]=bv.x; Bs[bk][bnq*4+1]=bv.y; Bs[bk][bnq*4+2]=bv.z; Bs[bk][bnq*4+3]=bv.w;
    }
    __syncthreads();
    #pragma unroll
    for (int k=0;k<16;++k) {
      float a0=As[k][tm*4+0], a1=As[k][tm*4+1], a2=As[k][tm*4+2], a3=As[k][tm*4+3];
      float b0=Bs[k][tn*4+0], b1=Bs[k][tn*4+1], b2=Bs[k][tn*4+2], b3=Bs[k][tn*4+3];
      acc[0][0]=fmaf(a0,b0,acc[0][0]); acc[0][1]=fmaf(a0,b1,acc[0][1]);
      acc[0][2]=fmaf(a0,b2,acc[0][2]); acc[0][3]=fmaf(a0,b3,acc[0][3]);
      acc[1][0]=fmaf(a1,b0,acc[1][0]); acc[1][1]=fmaf(a1,b1,acc[1][1]);
      acc[1][2]=fmaf(a1,b2,acc[1][2]); acc[1][3]=fmaf(a1,b3,acc[1][3]);
      acc[2][0]=fmaf(a2,b0,acc[2][0]); acc[2][1]=fmaf(a2,b1,acc[2][1]);
      acc[2][2]=fmaf(a2,b2,acc[2][2]); acc[2][3]=fmaf(a2,b3,acc[2][3]);
      acc[3][0]=fmaf(a3,b0,acc[3][0]); acc[3][1]=fmaf(a3,b1,acc[3][1]);
      acc[3][2]=fmaf(a3,b2,acc[3][2]); acc[3][3]=fmaf(a3,b3,acc[3][3]);
    }
    __syncthreads();
  }
  for (int i=0;i<4;++i)
    for (int j2=0;j2<4;++j2) {
      int r = row0+tm*4+i, c = col0+tn*4+j2;
      if (c<N) {
        float v = acc[i][j2] + (bias? bias[c]:0.f);
        if (act==1) v = fmaxf(v,0.f);
        else if (act==2) v = 1.f/(1.f+expf(-v));
        C[(size_t)r*ldc + c] = v;
      }
    }
}

// ---------------------------------------------------------------------------
// Fence-free global barrier. All cross-WG data moves via sc0sc1 write-through
// (globally visible once vmcnt acked) -> no cache maintenance needed here.
__device__ __forceinline__ void gbar(int n, int wg, int& alive, int* s_bail) {
  asm volatile("s_waitcnt vmcnt(0)" ::: "memory");
  __syncthreads();
  int* bars = (int*)(g_mem+OBARS);
  if (alive) {
    if (threadIdx.x==0) atomicAdd(&bars[(wg>>3)*16], 1);
    if (threadIdx.x<32) {
      const int target = n*8;
      int guard = 0;
      while (__hip_atomic_load(&bars[threadIdx.x*16], __ATOMIC_RELAXED, __HIP_MEMORY_SCOPE_AGENT) < target) {
        __builtin_amdgcn_s_sleep(2);
        if (++guard > (1<<20)) { *s_bail = 1; break; }
      }
    }
  }
  __syncthreads();
  if (*s_bail) alive = 0;
  __syncthreads();
}

// ---------------------------------------------------------------------------
__global__ __launch_bounds__(256,1) void k_scan(
    const float* __restrict__ w_hh, const float* __restrict__ b_hh,
    const float* __restrict__ aux_wih, const float* __restrict__ aux_whh,
    const float* __restrict__ aux_bhh,
    const float* __restrict__ ifc_b1, const float* __restrict__ ifc_w2,
    const float* __restrict__ ifc_b2,
    const float* __restrict__ hfc_w1, const float* __restrict__ hfc_b1,
    const float* __restrict__ hfc_w2, const float* __restrict__ hfc_b2,
    const float* __restrict__ gum_i, const float* __restrict__ gum_h,
    const int* __restrict__ length)
{
  const int wg  = blockIdx.x;
  const int tid = threadIdx.x;
  float* const mem = g_mem;

  extern __shared__ __align__(16) float blob[];   // 149504 B dynamic
  __shared__ int s_bail;
  if (tid==0) s_bail = 0;

  int alive = 1;

  // ===================== one-time per-role setup ===========================
  if (wg < 192) {
    // G-WG: stage 64-col w_hh slice -> blob[0..32767] ([512][64])
    const int cg = wg>>2;
    const int isG2c = (cg>=24);
    const int rowb  = isG2c? 512 : 0;
    const int colb  = cg*64 - (isG2c? 1536 : 0);
    for (int i4 = tid; i4 < 8192; i4 += 256) {
      const int k = i4>>4, c4 = i4&15;
      const float4 v = *(const float4*)&w_hh[(size_t)(rowb+k)*1536 + colb + c4*4];
      *(float4*)&blob[k*64 + c4*4] = v;
    }
  } else if (wg < 224) {
    // aux-WG: stage gate-sliced aux weights: s_aw [512][16], s_aw2 [130][16]
    const int a = wg-192;
    const int c0 = (a*130)>>5, c1 = ((a+1)*130)>>5;
    const int nc = c1-c0;
    const int w3 = nc*3;
    float* s_aw  = blob;
    float* s_aw2 = blob + 8192;
    for (int i = tid; i < 512*w3; i += 256) {
      const int k = i/w3, r = i - k*w3;
      const int rcl = r/3, gate = r - rcl*3;              // {0,1,2} = r,z,n
      const int gc = (gate==2? 260 : gate*130) + (c0+rcl);
      s_aw[k*16 + r] = aux_wih[(size_t)(512+k)*390 + gc];
    }
    for (int i = tid; i < 130*w3; i += 256) {
      const int k = i/w3, r = i - k*w3;
      const int rcl = r/3, q = r - rcl*3;
      const int gate = (q==2)? 3 : q;                     // {0,1,3}
      const int gc = (gate==3? 260 : gate*130) + (c0+rcl);
      s_aw2[k*16 + r] = aux_whh[(size_t)k*390 + gc];
    }
  } else {
    // batch-WG: init LDS caches: rows = MLP(0), lu=NEG, islot=-1
    float* s_c0 = blob + 512;          // [64][65]
    float* s_c1 = blob + 4672;         // [64][65]
    float* s_lu = blob + 8832;         // [2][64]
    int*   s_islot = (int*)(blob + 8960);
    if (tid < 64) {
      float si = ifc_b2[tid], sh = hfc_b2[tid];
      #pragma unroll 8
      for (int q=0;q<32;++q){
        si = fmaf(fmaxf(ifc_b1[q],0.f), ifc_w2[(size_t)q*64+tid], si);
        sh = fmaf(fmaxf(hfc_b1[q],0.f), hfc_w2[(size_t)q*64+tid], sh);
      }
      const float i0 = sigm(si), h0 = sigm(sh);
      for (int m=0;m<64;++m){ s_c0[m*65+tid]=i0; s_c1[m*65+tid]=h0; }
    }
    if (tid < 128) s_lu[tid] = NEGV;
    if (tid < 64)  s_islot[tid] = -1;
  }
  __syncthreads();

  // ===================== scan ==============================================
  #pragma unroll 1
  for (int t=0; t<128; ++t) {
    const float* htc = mem + OHTS + (size_t)(t&1)*16384;       // carry h [32][512]
    float*       htn = mem + OHTS + (size_t)((t+1)&1)*16384;
    const float* axc = mem + OAX  + (size_t)(t&1)*4224;        // carry aux [32][132]
    float*       axn = mem + OAX  + (size_t)((t+1)&1)*4224;

    // ---------------- H-phase ----------------
    if (wg < 192) {
      float* s_w   = blob;             // [512][64]
      float* s_h   = blob + 32768;     // [512][8]
      float* s_red = blob + 36864;     // [2][4][64]
      const int cg = wg>>2, bg = wg&3;
      // stage h slice (8 batches), coalesced sc1 reads
      {
        const float* hb = htc + (size_t)(bg*8)*512;
        for (int i=tid; i<4096; i+=256){
          const int bb=i>>9, k=i&511;
          s_h[k*8+bb] = ldc1(hb + bb*512 + k);
        }
      }
      __syncthreads();
      const int wave = tid>>6, lane = tid&63;
      const int vcol = cg*64 + lane;
      const int isG2 = vcol>=1536;
      const int col  = isG2? vcol-1536 : vcol;
      const int bh = wave>>1, kh = wave&1;
      const int b0l = bh*4;
      float a0=0.f,a1=0.f,a2=0.f,a3=0.f;
      const int kbeg = kh*256;
      #pragma unroll 8
      for (int k=kbeg; k<kbeg+256; ++k) {
        const float w = s_w[k*64 + lane];
        const float4 hv = *(const float4*)&s_h[k*8 + b0l];
        a0 = fmaf(w,hv.x,a0); a1 = fmaf(w,hv.y,a1);
        a2 = fmaf(w,hv.z,a2); a3 = fmaf(w,hv.w,a3);
      }
      if (kh) {
        s_red[(bh*4+0)*64+lane]=a0; s_red[(bh*4+1)*64+lane]=a1;
        s_red[(bh*4+2)*64+lane]=a2; s_red[(bh*4+3)*64+lane]=a3;
      }
      __syncthreads();
      if (!kh) {
        a0+=s_red[(bh*4+0)*64+lane]; a1+=s_red[(bh*4+1)*64+lane];
        a2+=s_red[(bh*4+2)*64+lane]; a3+=s_red[(bh*4+3)*64+lane];
        const float bias = isG2 ? 0.f : b_hh[vcol];
        float* Gp = mem + (isG2? OG2 : OG1);
        const int b0 = bg*8 + bh*4;
        stc1(&Gp[(size_t)(b0+0)*1536+col], a0+bias);
        stc1(&Gp[(size_t)(b0+1)*1536+col], a1+bias);
        stc1(&Gp[(size_t)(b0+2)*1536+col], a2+bias);
        stc1(&Gp[(size_t)(b0+3)*1536+col], a3+bias);
      }
    } else if (wg < 224) {
      const int a = wg-192;
      const int c0 = (a*130)>>5, c1 = ((a+1)*130)>>5;
      const int nc = c1-c0;
      const float* s_aw  = blob;
      const float* s_aw2 = blob + 8192;
      float* s_h2 = blob + 10272;      // [512][33]
      float* s_ax = blob + 27168;      // [130][33]
      float* s_sp = blob + 31464;      // [5][4][2][32]
      // stage full h + aux carry (coalesced sc1)
      for (int i=tid; i<16384; i+=256){ const int b=i>>9, k=i&511; s_h2[k*33+b]=ldc1(htc + b*512 + k); }
      for (int i=tid; i<4160;  i+=256){ const int b=i/130, c=i-b*130; s_ax[c*33+b]=ldc1(axc + b*132 + c); }
      __syncthreads();
      const int nt = nc*256;
      for (int task=tid; task<nt; task+=256) {
        const int b=task&31, kh=(task>>5)&1, gate=(task>>6)&3, rcl=task>>8;
        float acc=0.f;
        if (gate != 3) {
          const int kb = kh*256;
          #pragma unroll 8
          for (int k=kb;k<kb+256;++k) acc = fmaf(s_h2[k*33+b], s_aw[k*16 + rcl*3+gate], acc);
        }
        if (gate != 2) {
          const int q = (gate==3)? 2 : gate;
          const int kb = kh*65;
          for (int k=kb;k<kb+65;++k) acc = fmaf(s_ax[k*33+b], s_aw2[k*16 + rcl*3+q], acc);
        }
        s_sp[((rcl*4+gate)*2+kh)*32 + b] = acc;
      }
      __syncthreads();
      for (int task=tid; task<nc*32; task+=256) {
        const int b=task&31, rcl=task>>5;
        const int c=c0+rcl;
        const size_t base=((size_t)t*32+b)*390;
        #define SP(g,k) s_sp[((rcl*4+(g))*2+(k))*32+b]
        const float r = sigm(mem[OGIXA+base+c]     + aux_bhh[c]     + SP(0,0)+SP(0,1));
        const float z = sigm(mem[OGIXA+base+130+c] + aux_bhh[130+c] + SP(1,0)+SP(1,1));
        const float gin = mem[OGIXA+base+260+c] + SP(2,0)+SP(2,1);
        const float ghn = aux_bhh[260+c]        + SP(3,0)+SP(3,1);
        #undef SP
        const float n = tanhf(gin + r*ghn);
        stc1(&mem[ORH + (size_t)c*32 + b], (1.f-z)*n + z*s_ax[c*33+b]);
      }
    } else {
      // batch-WG H: stage h[b], compute hidden = relu(h @ hfc_w1 + b1)
      const int b = wg-224;
      float* s_h1  = blob;             // [512]
      float* s_hid = blob + 9024;      // [32]
      float* s_ph  = blob + 9472;      // [32][9]
      for (int i=tid; i<512; i+=256) s_h1[i] = ldc1(htc + b*512 + i);
      __syncthreads();
      {
        const int j = tid&31, kq = tid>>5;
        float acc=0.f;
        const int kb = kq*64;
        #pragma unroll 8
        for (int k=kb;k<kb+64;++k) acc = fmaf(s_h1[k], hfc_w1[(size_t)k*32+j], acc);
        s_ph[j*9+kq]=acc;
      }
      __syncthreads();
      if (tid<32) {
        float s = hfc_b1[tid];
        #pragma unroll
        for (int q=0;q<8;++q) s += s_ph[tid*9+q];
        s_hid[tid] = fmaxf(s,0.f);
      }
    }
    gbar(2*t+1, wg, alive, &s_bail);

    // ---------------- S-phase (batch-WGs only) ----------------
    if (wg >= 224) {
      const int b = wg-224;
      float* s_h1  = blob;
      float* s_c0  = blob + 512;
      float* s_c1  = blob + 4672;
      float* s_lu  = blob + 8832;
      int*   s_islot = (int*)(blob + 8960);
      float* s_hid = blob + 9024;
      float* s_rhs = blob + 9056;      // [132]
      float* s_sv  = blob + 9216;      // [128]
      int*   s_si  = (int*)(blob + 9344);
      float* s_phx = blob + 9472;      (void)s_phx;
      int*   s_sel = (int*)(blob + 9760);

      if (tid<130) s_rhs[tid] = ldc1(&mem[ORH + (size_t)tid*32 + b]);
      __syncthreads();
      if (tid<128) {
        const int head=tid>>6, m=tid&63;
        const float* C = head? s_c1 : s_c0;
        const float* rh = s_rhs + head*65;
        float acc=0.f;
        #pragma unroll 16
        for (int k=0;k<64;++k) acc = fmaf(rh[k], C[m*65+k], acc);
        acc += rh[64]*sigm(s_lu[head*64+m]);
        acc += (head? gum_h:gum_i)[((size_t)t*32+b)*64+m];
        s_sv[tid]=acc; s_si[tid]=m;
      }
      __syncthreads();
      for (int off=32; off>0; off>>=1) {
        if (tid<128 && (tid&63)<off) {
          const float v2=s_sv[tid+off]; const int i2=s_si[tid+off];
          if (v2>s_sv[tid] || (v2==s_sv[tid] && i2<s_si[tid])) { s_sv[tid]=v2; s_si[tid]=i2; }
        }
        __syncthreads();
      }
      if (tid==0) {
        const int isel=s_si[0], hsel=s_si[64];
        s_sel[0]=isel; s_sel[1]=hsel; s_sel[2]=s_islot[isel];
        s_sel[3]=(t<64)? t : isel; s_sel[4]=(t<64)? t : hsel;
      }
      __syncthreads();
      const int isel=s_sel[0], hsel=s_sel[1], tsel=s_sel[2];
      const int wsi=s_sel[3], wsh=s_sel[4];
      const int len = length[b];

      // gate combine over all 1536 cols (512 g-triples, 2 per thread)
      for (int g=tid; g<512; g+=256) {
        const size_t base=((size_t)t*32+b)*1536;
        float wi0=mem[OGIXM+base+g], wi1=mem[OGIXM+base+512+g], wi2=mem[OGIXM+base+1024+g];
        if (tsel>=0) {
          const size_t pb=((size_t)tsel*32+b)*1536;
          wi0+=mem[OPI+pb+g]; wi1+=mem[OPI+pb+512+g]; wi2+=mem[OPI+pb+1024+g];
        }
        const size_t g1b=(size_t)b*1536;
        const float q10=ldc1(&mem[OG1+g1b+g]), q11=ldc1(&mem[OG1+g1b+512+g]), q12=ldc1(&mem[OG1+g1b+1024+g]);
        const float q20=ldc1(&mem[OG2+g1b+g]), q21=ldc1(&mem[OG2+g1b+512+g]), q22=ldc1(&mem[OG2+g1b+1024+g]);
        const size_t hb2=((size_t)b*64+hsel)*1536;
        const float wh0=q10+mem[OHG2+hb2+g];
        const float wh1=q11+mem[OHG2+hb2+512+g];
        const float wh2=q12+mem[OHG2+hb2+1024+g];
        const float r=sigm(wi0+wh0), z=sigm(wi1+wh1);
        const float n=tanhf(wi2 + r*wh2);
        const float hold=s_h1[g];
        const float h1v=(1.f-z)*n + z*hold;
        const float hn = (t<len)? h1v : hold;
        stc1(&htn[(size_t)b*512+g], hn);
        mem[OYS + ((size_t)t*32+b)*512 + g] = hn;     // normal (read next kernel)
        const size_t wb2=((size_t)b*64+wsh)*1536;     // private: normal cached
        mem[OHG2+wb2+g]=q20; mem[OHG2+wb2+512+g]=q21; mem[OHG2+wb2+1024+g]=q22;
      }
      // aux carry publish
      if (tid<130) {
        const float oldv = ldc1(&axc[(size_t)b*132+tid]);
        stc1(&axn[(size_t)b*132+tid], (t<len)? s_rhs[tid] : oldv);
      }
      // local state updates (after scores consumed)
      if (tid<128) {
        const int head=tid>>6, m=tid&63;
        const int sel = head? hsel : isel;
        const float v = s_lu[tid];
        s_lu[tid] = (m==sel)? 0.f : (v-1.f);
      }
      if (tid<64) {
        s_c0[wsi*65+tid] = mem[OIMLPX + ((size_t)t*32+b)*64 + tid];
      } else if (tid<128) {
        const int j2=tid-64;
        float s = hfc_b2[j2];
        #pragma unroll 8
        for (int q=0;q<32;++q) s = fmaf(s_hid[q], hfc_w2[(size_t)q*64+j2], s);
        s_c1[wsh*65+j2] = sigm(s);
      } else if (tid==128) {
        s_islot[wsi] = t;
      }
    }
    gbar(2*t+2, wg, alive, &s_bail);
  }
}

// ---------------------------------------------------------------------------
extern "C" void kernel_launch(void* const* d_in, const int* in_sizes, int n_in,
                              void* d_out, int out_size, void* d_ws, size_t ws_size,
                              hipStream_t stream)
{
  (void)in_sizes; (void)n_in; (void)out_size; (void)d_ws; (void)ws_size;
  const float* x      = (const float*)d_in[0];
  const int*   length = (const int*)  d_in[1];
  const float* fc1_w  = (const float*)d_in[2];
  const float* fc1_b  = (const float*)d_in[3];
  const float* w_ih   = (const float*)d_in[4];
  const float* w_hh   = (const float*)d_in[5];
  const float* b_ih   = (const float*)d_in[6];
  const float* b_hh   = (const float*)d_in[7];
  const float* aux_wih= (const float*)d_in[8];
  const float* aux_whh= (const float*)d_in[9];
  const float* aux_bih= (const float*)d_in[10];
  const float* aux_bhh= (const float*)d_in[11];
  const float* ifc_w1 = (const float*)d_in[12];
  const float* ifc_b1 = (const float*)d_in[13];
  const float* ifc_w2 = (const float*)d_in[14];
  const float* ifc_b2 = (const float*)d_in[15];
  const float* hfc_w1 = (const float*)d_in[16];
  const float* hfc_b1 = (const float*)d_in[17];
  const float* hfc_w2 = (const float*)d_in[18];
  const float* hfc_b2 = (const float*)d_in[19];
  const float* fc_w   = (const float*)d_in[20];
  const float* fc_b   = (const float*)d_in[21];
  const float* gum_i  = (const float*)d_in[22];
  const float* gum_h  = (const float*)d_in[23];
  float* out = (float*)d_out;

  float* gm = nullptr;
  hipGetSymbolAddress((void**)&gm, HIP_SYMBOL(g_mem));

  static bool attr_done = false;
  if (!attr_done) {
    hipFuncSetAttribute((const void*)k_scan,
                        hipFuncAttributeMaxDynamicSharedMemorySize, 149504);
    attr_done = true;
  }

  k_init<<<2048,256,0,stream>>>();
  // xp = x @ fc1_w + fc1_b
  k_gemm<<<dim3(64,8),256,0,stream>>>(x,500, fc1_w,512, fc1_b, gm+OXP,512, 512,500, 0);
  // gix_main = xp @ w_ih[:512] + b_ih
  k_gemm<<<dim3(64,24),256,0,stream>>>(gm+OXP,512, w_ih,1536, b_ih, gm+OGIXM,1536, 1536,512, 0);
  // P_i = xp @ w_ih[512:]
  k_gemm<<<dim3(64,24),256,0,stream>>>(gm+OXP,512, w_ih+(size_t)512*1536,1536, nullptr, gm+OPI,1536, 1536,512, 0);
  // gix_aux = xp @ aux_wih[:512] + aux_bih
  k_gemm<<<dim3(64,7),256,0,stream>>>(gm+OXP,512, aux_wih,390, aux_bih, gm+OGIXA,390, 390,512, 0);
  // ihid = relu(xp @ ifc_w1 + ifc_b1)
  k_gemm<<<dim3(64,1),256,0,stream>>>(gm+OXP,512, ifc_w1,32, ifc_b1, gm+OIHID,32, 32,512, 1);
  // imlp_x = sigmoid(ihid @ ifc_w2 + ifc_b2)
  k_gemm<<<dim3(64,1),256,0,stream>>>(gm+OIHID,32, ifc_w2,64, ifc_b2, gm+OIMLPX,64, 64,32, 2);
  // scan: persistent kernel, 2 fence-free global barriers per step
  k_scan<<<NWG,256,149504,stream>>>(w_hh,b_hh,aux_wih,aux_whh,aux_bhh,
                                    ifc_b1,ifc_w2,ifc_b2,
                                    hfc_w1,hfc_b1,hfc_w2,hfc_b2,
                                    gum_i,gum_h,length);
  // out = ys @ fc_w + fc_b
  k_gemm<<<dim3(64,1),256,0,stream>>>(gm+OYS,512, fc_w,48, fc_b, out,48, 48,512, 0);
}